// Round 13
// baseline (7304.233 us; speedup 1.0000x reference)
//
#include <hip/hip_runtime.h>

// ---------------- types & helpers ----------------
typedef _Float16 half_t;
typedef _Float16 __attribute__((ext_vector_type(2))) half2_t;

__device__ __forceinline__ float fdot2_(half2_t a, half2_t b, float c) {
#if __has_builtin(__builtin_amdgcn_fdot2)
    return __builtin_amdgcn_fdot2(a, b, c, false);
#else
    return c + (float)a[0] * (float)b[0] + (float)a[1] * (float)b[1];
#endif
}
__device__ __forceinline__ half2_t h2(float a, float b) {
    half2_t r; r[0] = (half_t)a; r[1] = (half_t)b; return r;
}
__device__ __forceinline__ half2_t bc2(unsigned int u) {
    return __builtin_bit_cast(half2_t, u);
}
__device__ __forceinline__ unsigned int pk2(float a, float b) {
    return __builtin_bit_cast(unsigned int, h2(a, b));
}
__device__ __forceinline__ float sigm(float x) { return 1.0f / (1.0f + __expf(-x)); }
__device__ __forceinline__ float tanh_(float x) { return 1.0f - 2.0f / (1.0f + __expf(2.0f * x)); }
__device__ __forceinline__ unsigned int packbf2(float a, float b) {
    unsigned int ua = __float_as_uint(a);
    ua = (ua + 0x7fffu + ((ua >> 16) & 1u)) >> 16;
    unsigned int ub = __float_as_uint(b);
    ub = (ub + 0x7fffu + ((ub >> 16) & 1u)) >> 16;
    return ua | (ub << 16);
}
__device__ __forceinline__ float blo(unsigned int u) { return __uint_as_float(u << 16); }
__device__ __forceinline__ float bhi(unsigned int u) { return __uint_as_float(u & 0xffff0000u); }

// ---------------- LSTM layer 1 (bidir, K=40 fused): 2 batches / WG ----------------
// 512 thr; weight regs (84 u32) shared across both batches; activation 256-wide.
__global__ __launch_bounds__(512, 1) void lstm1_k(
    const float* __restrict__ utter,
    const float* __restrict__ wih_f, const float* __restrict__ whh_f,
    const float* __restrict__ bih_f, const float* __restrict__ bhh_f,
    const float* __restrict__ wih_r, const float* __restrict__ whh_r,
    const float* __restrict__ bih_r, const float* __restrict__ bhh_r,
    unsigned short* __restrict__ Hf, unsigned short* __restrict__ Hr)
{
    const int tid = threadIdx.x;
    const int pair = blockIdx.x & 31;
    const int dir  = blockIdx.x >> 5;
    const int b0 = pair * 2;
    const float* wih = dir ? wih_r : wih_f;
    const float* whh = dir ? whh_r : whh_f;
    const float* bih = dir ? bih_r : bih_f;
    const float* bhh = dir ? bhh_r : bhh_f;
    unsigned short* Hout = dir ? Hr : Hf;

    __shared__ float acts[2][512];
    __shared__ __align__(16) half_t h_h[2][128];
    __shared__ __align__(16) half_t x3[3][2][48];

    const int j = tid;
    const int gt = tid >> 7;
    unsigned int wr2[64];
    {
        const float4* wp = reinterpret_cast<const float4*>(whh + j * 128);
#pragma unroll
        for (int m = 0; m < 32; ++m) {
            float4 v = wp[m];
            wr2[2 * m]     = pk2(v.x, v.y);
            wr2[2 * m + 1] = pk2(v.z, v.w);
        }
    }
    unsigned int wx2[20];
    {
        const float4* xp = reinterpret_cast<const float4*>(wih + j * 40);
#pragma unroll
        for (int q = 0; q < 10; ++q) {
            float4 v = xp[q];
            wx2[2 * q]     = pk2(v.x, v.y);
            wx2[2 * q + 1] = pk2(v.z, v.w);
        }
    }
    const float bias = bih[j] + bhh[j];
    float c = 0.0f;
    if (tid < 256) h_h[tid >> 7][tid & 127] = (half_t)0.0f;
    if (tid >= 256 && tid < 416) {         // init x rows 0,1 for both batches
        int u = tid - 256;                  // 0..159
        int sub = u / 80, rem = u % 80;
        int row = rem / 40, col = rem % 40;
        int tt = dir ? (2047 - row) : row;
        x3[row][sub][col] = (half_t)utter[((size_t)(b0 + sub) * 2048 + tt) * 40 + col];
    }
    __syncthreads();

    for (int t = 0; t < 2048; ++t) {
        const int cur = t % 3;
        const int nx2 = (t + 2) % 3;
        float xn = 0.0f;
        const int tq = tid - 256;
        const int psub = tq / 40, pcol = tq % 40;
        if (tq >= 0 && tq < 80) {
            int tn = (t + 2 < 2048) ? (t + 2) : 2047;
            int ttn = dir ? (2047 - tn) : tn;
            xn = utter[((size_t)(b0 + psub) * 2048 + ttn) * 40 + pcol];
        }
        // ---- batch 0 gate dot
        {
            float g0 = bias, g1 = 0.f, g2 = 0.f, g3 = 0.f;
            const uint4* x4p = reinterpret_cast<const uint4*>(&x3[cur][0][0]);
#pragma unroll
            for (int q = 0; q < 5; ++q) {
                uint4 u = x4p[q];
                g0 = fdot2_(bc2(wx2[4 * q]),     bc2(u.x), g0);
                g1 = fdot2_(bc2(wx2[4 * q + 1]), bc2(u.y), g1);
                g2 = fdot2_(bc2(wx2[4 * q + 2]), bc2(u.z), g2);
                g3 = fdot2_(bc2(wx2[4 * q + 3]), bc2(u.w), g3);
            }
            const uint4* h4p = reinterpret_cast<const uint4*>(&h_h[0][0]);
#pragma unroll
            for (int q = 0; q < 16; ++q) {
                uint4 u = h4p[q];
                g0 = fdot2_(bc2(wr2[4 * q]),     bc2(u.x), g0);
                g1 = fdot2_(bc2(wr2[4 * q + 1]), bc2(u.y), g1);
                g2 = fdot2_(bc2(wr2[4 * q + 2]), bc2(u.z), g2);
                g3 = fdot2_(bc2(wr2[4 * q + 3]), bc2(u.w), g3);
            }
            float g = (g0 + g1) + (g2 + g3);
            acts[0][j] = (gt == 2) ? tanh_(g) : sigm(g);
        }
        // ---- batch 1 gate dot
        {
            float g0 = bias, g1 = 0.f, g2 = 0.f, g3 = 0.f;
            const uint4* x4p = reinterpret_cast<const uint4*>(&x3[cur][1][0]);
#pragma unroll
            for (int q = 0; q < 5; ++q) {
                uint4 u = x4p[q];
                g0 = fdot2_(bc2(wx2[4 * q]),     bc2(u.x), g0);
                g1 = fdot2_(bc2(wx2[4 * q + 1]), bc2(u.y), g1);
                g2 = fdot2_(bc2(wx2[4 * q + 2]), bc2(u.z), g2);
                g3 = fdot2_(bc2(wx2[4 * q + 3]), bc2(u.w), g3);
            }
            const uint4* h4p = reinterpret_cast<const uint4*>(&h_h[1][0]);
#pragma unroll
            for (int q = 0; q < 16; ++q) {
                uint4 u = h4p[q];
                g0 = fdot2_(bc2(wr2[4 * q]),     bc2(u.x), g0);
                g1 = fdot2_(bc2(wr2[4 * q + 1]), bc2(u.y), g1);
                g2 = fdot2_(bc2(wr2[4 * q + 2]), bc2(u.z), g2);
                g3 = fdot2_(bc2(wr2[4 * q + 3]), bc2(u.w), g3);
            }
            float g = (g0 + g1) + (g2 + g3);
            acts[1][j] = (gt == 2) ? tanh_(g) : sigm(g);
        }
        __syncthreads();
        if (tid < 256) {
            int sub = tid >> 7, jj = tid & 127;
            float i_ = acts[sub][jj];
            float f_ = acts[sub][128 + jj];
            float g_ = acts[sub][256 + jj];
            float o_ = acts[sub][384 + jj];
            c = f_ * c + i_ * g_;
            float hh = o_ * tanh_(c);
            half_t hx = (half_t)hh;
            h_h[sub][jj] = hx;
            int tt = dir ? (2047 - t) : t;
            Hout[((size_t)tt * 64 + b0 + sub) * 128 + jj] = __builtin_bit_cast(unsigned short, hx);
        } else if (tq < 80) {
            x3[nx2][psub][pcol] = (half_t)xn;
        }
        __syncthreads();
    }
}

// ---------------- LSTM layers 2/3: 2 batches / WG, P f16 streamed ----------------
__global__ __launch_bounds__(512, 1) void lstm_k(
    const unsigned short* __restrict__ Ph,   // [b][T][512] f16 bits
    const float* __restrict__ whh,
    void* __restrict__ Hout, int T, int outHalf)
{
    const int tid = threadIdx.x;
    const int b0 = blockIdx.x * 2;
    const int j = tid;
    const int gt = tid >> 7;
    __shared__ float acts[2][512];
    __shared__ __align__(16) half_t h_h[2][128];
    unsigned int wr2[64];
    {
        const float4* wp = reinterpret_cast<const float4*>(whh + j * 128);
#pragma unroll
        for (int m = 0; m < 32; ++m) {
            float4 v = wp[m];
            wr2[2 * m]     = pk2(v.x, v.y);
            wr2[2 * m + 1] = pk2(v.z, v.w);
        }
    }
    float c = 0.0f;
    if (tid < 256) h_h[tid >> 7][tid & 127] = (half_t)0.0f;
    const size_t pb0 = (size_t)b0 * T, pb1 = (size_t)(b0 + 1) * T;
    float p0_cur = (float)__builtin_bit_cast(half_t, Ph[(pb0 + 0) * 512 + j]);
    float p0_n1  = (float)__builtin_bit_cast(half_t, Ph[(pb0 + 1) * 512 + j]);
    float p1_cur = (float)__builtin_bit_cast(half_t, Ph[(pb1 + 0) * 512 + j]);
    float p1_n1  = (float)__builtin_bit_cast(half_t, Ph[(pb1 + 1) * 512 + j]);
    __syncthreads();
    for (int t = 0; t < T; ++t) {
        int tn = (t + 2 < T) ? (t + 2) : (T - 1);
        float p0_n2 = (float)__builtin_bit_cast(half_t, Ph[(pb0 + tn) * 512 + j]);
        float p1_n2 = (float)__builtin_bit_cast(half_t, Ph[(pb1 + tn) * 512 + j]);
        {
            float g0 = p0_cur, g1 = 0.f, g2 = 0.f, g3 = 0.f;
            const uint4* h4p = reinterpret_cast<const uint4*>(&h_h[0][0]);
#pragma unroll
            for (int q = 0; q < 16; ++q) {
                uint4 u = h4p[q];
                g0 = fdot2_(bc2(wr2[4 * q]),     bc2(u.x), g0);
                g1 = fdot2_(bc2(wr2[4 * q + 1]), bc2(u.y), g1);
                g2 = fdot2_(bc2(wr2[4 * q + 2]), bc2(u.z), g2);
                g3 = fdot2_(bc2(wr2[4 * q + 3]), bc2(u.w), g3);
            }
            float g = (g0 + g1) + (g2 + g3);
            acts[0][j] = (gt == 2) ? tanh_(g) : sigm(g);
        }
        {
            float g0 = p1_cur, g1 = 0.f, g2 = 0.f, g3 = 0.f;
            const uint4* h4p = reinterpret_cast<const uint4*>(&h_h[1][0]);
#pragma unroll
            for (int q = 0; q < 16; ++q) {
                uint4 u = h4p[q];
                g0 = fdot2_(bc2(wr2[4 * q]),     bc2(u.x), g0);
                g1 = fdot2_(bc2(wr2[4 * q + 1]), bc2(u.y), g1);
                g2 = fdot2_(bc2(wr2[4 * q + 2]), bc2(u.z), g2);
                g3 = fdot2_(bc2(wr2[4 * q + 3]), bc2(u.w), g3);
            }
            float g = (g0 + g1) + (g2 + g3);
            acts[1][j] = (gt == 2) ? tanh_(g) : sigm(g);
        }
        __syncthreads();
        if (tid < 256) {
            int sub = tid >> 7, jj = tid & 127;
            float i_ = acts[sub][jj];
            float f_ = acts[sub][128 + jj];
            float g_ = acts[sub][256 + jj];
            float o_ = acts[sub][384 + jj];
            c = f_ * c + i_ * g_;
            float hh = o_ * tanh_(c);
            half_t hx = (half_t)hh;
            h_h[sub][jj] = hx;
            size_t oi = ((size_t)t * 64 + b0 + sub) * 128 + jj;
            if (outHalf) ((unsigned short*)Hout)[oi] = __builtin_bit_cast(unsigned short, hx);
            else         ((float*)Hout)[oi] = hh;
        }
        __syncthreads();
        p0_cur = p0_n1; p0_n1 = p0_n2;
        p1_cur = p1_n1; p1_n1 = p1_n2;
    }
}

// ---------------- conv1d kernel=2 stride=2, f16 inputs ----------------
template <int CIN>
__global__ __launch_bounds__(128) void conv_k(
    const unsigned short* __restrict__ HA, const unsigned short* __restrict__ HB,
    const float* __restrict__ W, const float* __restrict__ bias,
    float* __restrict__ out, int Tout)
{
    __shared__ __align__(16) float xin[64 * CIN];
    const int b = blockIdx.x;
    const int t0 = blockIdx.y * 32;
    const int tid = threadIdx.x;
    for (int idx = tid; idx < 64 * CIN; idx += 128) {
        int tl = idx / CIN, ci = idx % CIN;
        int tau = t0 * 2 + tl;
        unsigned short u;
        if constexpr (CIN == 256) {
            u = (ci < 128) ? HA[(size_t)tau * 8192 + b * 128 + ci]
                           : HB[(size_t)tau * 8192 + b * 128 + (ci - 128)];
        } else {
            u = HA[(size_t)tau * 8192 + b * 128 + ci];
        }
        xin[idx] = (float)__builtin_bit_cast(half_t, u);
    }
    __syncthreads();
    const int co = tid;
    float acc[32];
#pragma unroll
    for (int u = 0; u < 32; ++u) acc[u] = 0.0f;
    const float4* Wrow4 = reinterpret_cast<const float4*>(W + (size_t)co * 2 * CIN);
    const float4* xin4 = reinterpret_cast<const float4*>(xin);
    for (int c4 = 0; c4 < CIN / 4; ++c4) {
        float4 wA = Wrow4[2 * c4];
        float4 wB = Wrow4[2 * c4 + 1];
#pragma unroll
        for (int u = 0; u < 32; ++u) {
            float4 x0 = xin4[(2 * u) * (CIN / 4) + c4];
            float4 x1 = xin4[(2 * u + 1) * (CIN / 4) + c4];
            acc[u] += wA.x * x0.x + wA.y * x1.x + wA.z * x0.y + wA.w * x1.y
                    + wB.x * x0.z + wB.y * x1.z + wB.z * x0.w + wB.w * x1.w;
        }
    }
    float bs = bias[co];
#pragma unroll
    for (int u = 0; u < 32; ++u)
        out[((size_t)b * Tout + t0 + u) * 128 + co] = acc[u] + bs;
}

// ---------------- generic f32 GEMM ----------------
// mode 0: C f32 [m][N]; mode 1: transposed f32 C[(b*N+n)*Tdim+t], m=t*64+b; mode 2: C f16 [m][N]
__global__ __launch_bounds__(256) void gemm_k(
    const float* __restrict__ A, const float* __restrict__ W, int ldw,
    const float* __restrict__ bias1, const float* __restrict__ bias2,
    void* __restrict__ C, int M, int N, int K, int mode, int Tdim)
{
    __shared__ __align__(16) float As[16][68];
    __shared__ __align__(16) float Ws[16][68];
    const int tid = threadIdx.x;
    const int m0 = blockIdx.x * 64, n0 = blockIdx.y * 64;
    const int kk = tid & 15, mm = tid >> 4;
    const int tm = tid & 15, tn = tid >> 4;
    float acc[4][4];
#pragma unroll
    for (int i = 0; i < 4; ++i)
#pragma unroll
        for (int jj = 0; jj < 4; ++jj) acc[i][jj] = 0.0f;

    for (int k0 = 0; k0 < K; k0 += 16) {
#pragma unroll
        for (int r = 0; r < 4; ++r) {
            As[kk][mm + 16 * r] = A[(size_t)(m0 + mm + 16 * r) * K + k0 + kk];
            Ws[kk][mm + 16 * r] = W[(size_t)(n0 + mm + 16 * r) * ldw + k0 + kk];
        }
        __syncthreads();
#pragma unroll
        for (int q = 0; q < 16; ++q) {
            float4 a = reinterpret_cast<const float4*>(&As[q][0])[tm];
            float4 w = reinterpret_cast<const float4*>(&Ws[q][0])[tn];
            acc[0][0] += a.x * w.x; acc[0][1] += a.x * w.y; acc[0][2] += a.x * w.z; acc[0][3] += a.x * w.w;
            acc[1][0] += a.y * w.x; acc[1][1] += a.y * w.y; acc[1][2] += a.y * w.z; acc[1][3] += a.y * w.w;
            acc[2][0] += a.z * w.x; acc[2][1] += a.z * w.y; acc[2][2] += a.z * w.z; acc[2][3] += a.z * w.w;
            acc[3][0] += a.w * w.x; acc[3][1] += a.w * w.y; acc[3][2] += a.w * w.z; acc[3][3] += a.w * w.w;
        }
        __syncthreads();
    }
    float bv[4];
#pragma unroll
    for (int jj = 0; jj < 4; ++jj) {
        int n = n0 + tn * 4 + jj;
        float v = 0.0f;
        if (bias1) v += bias1[n];
        if (bias2) v += bias2[n];
        bv[jj] = v;
    }
#pragma unroll
    for (int i = 0; i < 4; ++i) {
        int m = m0 + tm * 4 + i;
#pragma unroll
        for (int jj = 0; jj < 4; ++jj) {
            int n = n0 + tn * 4 + jj;
            float v = acc[i][jj] + bv[jj];
            if (mode == 0) {
                ((float*)C)[(size_t)m * N + n] = v;
            } else if (mode == 1) {
                int bb = m & 63, tt = m >> 6;
                ((float*)C)[((size_t)bb * N + n) * Tdim + tt] = v;
            } else {
                ((unsigned short*)C)[(size_t)m * N + n] =
                    __builtin_bit_cast(unsigned short, (half_t)v);
            }
        }
    }
}

// ---------------- gather emb[targets] rows ----------------
__global__ __launch_bounds__(512) void packemb_k(
    const int* __restrict__ targets, const float* __restrict__ emb,
    float* __restrict__ Ypack)
{
    int m = blockIdx.x;  // l*64 + b
    int l = m >> 6, b = m & 63;
    int tgt = targets[b * 256 + l];
    Ypack[(size_t)m * 512 + threadIdx.x] = emb[(size_t)tgt * 512 + threadIdx.x];
}

// ---------------- pack: rows -> coalesced [nq][rows][uint4] (decoder weights) ----------------
__global__ __launch_bounds__(256) void packq_k(
    const float* __restrict__ src, unsigned int* __restrict__ dst,
    int srcCols, int colOff, int nq, int rows)
{
    int g = blockIdx.x * 256 + threadIdx.x;
    if (g >= rows * nq * 4) return;
    int k = g & 3, t = g >> 2;
    int j = t % rows, q = t / rows;
    int p = q * 4 + k;
    const float* s = src + (size_t)j * srcCols + colOff + 2 * p;
    dst[g] = pk2(s[0], s[1]);
}

// ---------------- pack hv: hvT f32 [b][d][t] -> bf16 pairs [b][tq][d] ----------------
__global__ __launch_bounds__(1024) void packhv2_k(
    const float* __restrict__ hvT, unsigned int* __restrict__ hvq)
{
    int b = blockIdx.x;
    for (int it = 0; it < 32; ++it) {
        int idx = it * 1024 + threadIdx.x;       // 32768 = 256 tq x 128 d
        int tq = idx >> 7, d = idx & 127;
        const float* s = hvT + ((size_t)b * 128 + d) * 512 + 2 * tq;
        hvq[(size_t)b * 32768 + idx] = packbf2(s[0], s[1]);
    }
}

// ---------------- attention decoder v12: 512 thr, h-path weights in regs ----------------
__global__ __launch_bounds__(512, 1) void decoder_k(
    const float* __restrict__ Yp,
    const unsigned int* __restrict__ Wd,     // [2 path][16 q][512 j][4 k] u32
    const float* __restrict__ hk,            // f32 [t*64+b][128]
    const unsigned int* __restrict__ hvq,    // [b][256 tq][128 d] bf16 pairs
    const float* __restrict__ sh0, const float* __restrict__ sc0,
    float* __restrict__ SHs, float* __restrict__ Cs)
{
    __shared__ unsigned int hk_lds[512][66];   // 135168 B
    __shared__ float acts[512];
    __shared__ float pfl[512];
    __shared__ __align__(16) half_t sh_h[128];
    __shared__ __align__(16) float sc_f[128];
    __shared__ __align__(16) half_t c_h[128];
    __shared__ __align__(16) float att[512];
    __shared__ float red[8];

    const int tid = threadIdx.x;
    const int b = blockIdx.x;
    const int gt = tid >> 7;

    uint4 wh[16];
    {
        const uint4* W4 = reinterpret_cast<const uint4*>(Wd);
#pragma unroll
        for (int q = 0; q < 16; ++q) wh[q] = W4[q * 512 + tid];
    }
    const uint4* Wc4 = reinterpret_cast<const uint4*>(Wd) + 8192;  // c-path, streamed

    {
        const float4* hp = reinterpret_cast<const float4*>(hk + ((size_t)tid * 64 + b) * 128);
#pragma unroll
        for (int q = 0; q < 32; ++q) {
            float4 v = hp[q];
            hk_lds[tid][2 * q]     = packbf2(v.x, v.y);
            hk_lds[tid][2 * q + 1] = packbf2(v.z, v.w);
        }
    }
    float sc_r = 0.0f;
    if (tid < 128) {
        sh_h[tid] = (half_t)sh0[b * 128 + tid];
        sc_r = sc0[b * 128 + tid];
        sc_f[tid] = sc_r;
        c_h[tid] = (half_t)0.0f;
    }
    __syncthreads();

    const int wid = tid >> 6, lane = tid & 63;
    const int g4 = tid >> 7, d = tid & 127;
    const unsigned int* hvp = hvq + (size_t)b * 32768 + (size_t)(g4 * 64) * 128 + d;
    const float2* att2 = reinterpret_cast<const float2*>(att);
    float yp_cur = Yp[(size_t)b * 512 + tid];

    for (int l = 0; l < 255; ++l) {
        int lnxt = (l + 1 < 255) ? (l + 1) : l;
        float yp_nxt = Yp[((size_t)lnxt * 64 + b) * 512 + tid];
        {
            float g0 = yp_cur, g1 = 0.f, g2 = 0.f, g3 = 0.f;
            const uint4* s4 = reinterpret_cast<const uint4*>(sh_h);
#pragma unroll
            for (int q = 0; q < 16; ++q) {
                uint4 u = s4[q];
                g0 = fdot2_(bc2(wh[q].x), bc2(u.x), g0);
                g1 = fdot2_(bc2(wh[q].y), bc2(u.y), g1);
                g2 = fdot2_(bc2(wh[q].z), bc2(u.z), g2);
                g3 = fdot2_(bc2(wh[q].w), bc2(u.w), g3);
            }
            const uint4* c4 = reinterpret_cast<const uint4*>(c_h);
#pragma unroll
            for (int q = 0; q < 16; ++q) {
                uint4 w = Wc4[q * 512 + tid];
                uint4 u = c4[q];
                g0 = fdot2_(bc2(w.x), bc2(u.x), g0);
                g1 = fdot2_(bc2(w.y), bc2(u.y), g1);
                g2 = fdot2_(bc2(w.z), bc2(u.z), g2);
                g3 = fdot2_(bc2(w.w), bc2(u.w), g3);
            }
            float g = (g0 + g1) + (g2 + g3);
            acts[tid] = (gt == 2) ? tanh_(g) : sigm(g);
        }
        __syncthreads();                                   // B1
        if (tid < 128) {
            float i_ = acts[tid];
            float f_ = acts[128 + tid];
            float g_ = acts[256 + tid];
            float o_ = acts[384 + tid];
            sc_r = f_ * sc_r + i_ * g_;
            float hh = o_ * tanh_(sc_r);
            sh_h[tid] = (half_t)hh;
            sc_f[tid] = sc_r;
            SHs[((size_t)l * 64 + b) * 128 + tid] = hh;
        }
        __syncthreads();                                   // B2
        {
            float e0 = 0.f, e1 = 0.f, e2 = 0.f, e3 = 0.f;
            const uint2* hkr = reinterpret_cast<const uint2*>(&hk_lds[tid][0]);
            const float4* sc4 = reinterpret_cast<const float4*>(sc_f);
#pragma unroll
            for (int q = 0; q < 32; ++q) {
                uint2 u = hkr[q];
                float4 s = sc4[q];
                e0 += blo(u.x) * s.x; e1 += bhi(u.x) * s.y;
                e2 += blo(u.y) * s.z; e3 += bhi(u.y) * s.w;
            }
            float p = __expf((e0 + e1) + (e2 + e3));
            att[tid] = p;
            float ps = p;
#pragma unroll
            for (int off = 32; off; off >>= 1) ps += __shfl_xor(ps, off);
            if (lane == 0) red[wid] = ps;
        }
        __syncthreads();                                   // B3
        {
            float a0 = 0.f, a1 = 0.f;
#pragma unroll 8
            for (int i = 0; i < 64; i += 2) {
                unsigned int u0 = hvp[(size_t)i * 128];
                unsigned int u1 = hvp[(size_t)(i + 1) * 128];
                float2 w0 = att2[g4 * 64 + i];
                float2 w1 = att2[g4 * 64 + i + 1];
                a0 += blo(u0) * w0.x + bhi(u0) * w0.y;
                a1 += blo(u1) * w1.x + bhi(u1) * w1.y;
            }
            pfl[tid] = a0 + a1;
        }
        __syncthreads();                                   // B4
        if (tid < 128) {
            float S = ((red[0] + red[1]) + (red[2] + red[3]))
                    + ((red[4] + red[5]) + (red[6] + red[7]));
            float cv = (pfl[tid] + pfl[128 + tid] + pfl[256 + tid] + pfl[384 + tid]) / S;
            c_h[tid] = (half_t)cv;
            Cs[((size_t)l * 64 + b) * 128 + tid] = cv;
        }
        yp_cur = yp_nxt;
        __syncthreads();                                   // B5
    }
}

// ---------------- deferred output MLP + softmax ----------------
__global__ __launch_bounds__(256) void mlp_k(
    const float* __restrict__ SHs, const float* __restrict__ Cs,
    const float* __restrict__ w1, const float* __restrict__ b1,
    const float* __restrict__ w2, const float* __restrict__ b2,
    const float* __restrict__ w3, const float* __restrict__ b3,
    float* __restrict__ out)
{
    __shared__ float o_l[4][34];
    const int sub = threadIdx.x >> 6, lane = threadIdx.x & 63;
    const int m = blockIdx.x * 4 + sub;     // l*64 + b
    const int l = m >> 6, b = m & 63;
    if (lane < 34) {
        float o1 = b1[lane] + b2[lane];
        const float4* w1r = reinterpret_cast<const float4*>(w1 + lane * 128);
        const float4* w2r = reinterpret_cast<const float4*>(w2 + lane * 128);
        const float4* sh4 = reinterpret_cast<const float4*>(SHs + (size_t)m * 128);
        const float4* c4  = reinterpret_cast<const float4*>(Cs + (size_t)m * 128);
#pragma unroll 8
        for (int q = 0; q < 32; ++q) {
            float4 a = w1r[q], h = sh4[q], w = w2r[q], cc = c4[q];
            o1 += a.x * h.x + a.y * h.y + a.z * h.z + a.w * h.w
                + w.x * cc.x + w.y * cc.y + w.z * cc.z + w.w * cc.w;
        }
        o_l[sub][lane] = fmaxf(o1, 0.0f);
    }
    __syncthreads();
    if (lane < 34) {
        float zz = b3[lane];
        const float* w3r = w3 + lane * 34;
        for (int v = 0; v < 34; ++v) zz += w3r[v] * o_l[sub][v];
        __syncthreads();
        o_l[sub][lane] = zz;
        __syncthreads();
        float zm = o_l[sub][0];
        for (int v = 1; v < 34; ++v) zm = fmaxf(zm, o_l[sub][v]);
        float Ssum = 0.0f;
        for (int v = 0; v < 34; ++v) Ssum += __expf(o_l[sub][v] - zm);
        out[((size_t)b * 255 + l) * 34 + lane] = __expf(zz - zm) / Ssum;
    }
}

// ---------------- launch ----------------
extern "C" void kernel_launch(void* const* d_in, const int* in_sizes, int n_in,
                              void* d_out, int out_size, void* d_ws, size_t ws_size,
                              hipStream_t stream) {
    (void)in_sizes; (void)n_in; (void)out_size; (void)ws_size;
    const float* utter = (const float*)d_in[0];
    const int*   targets = (const int*)d_in[1];
    const float* wih_f = (const float*)d_in[2];
    const float* whh_f = (const float*)d_in[3];
    const float* bih_f = (const float*)d_in[4];
    const float* bhh_f = (const float*)d_in[5];
    const float* wih_r = (const float*)d_in[6];
    const float* whh_r = (const float*)d_in[7];
    const float* bih_r = (const float*)d_in[8];
    const float* bhh_r = (const float*)d_in[9];
    const float* c1w = (const float*)d_in[10];
    const float* c1b = (const float*)d_in[11];
    const float* wih1 = (const float*)d_in[12];
    const float* whh1 = (const float*)d_in[13];
    const float* bih1 = (const float*)d_in[14];
    const float* bhh1 = (const float*)d_in[15];
    const float* c2w = (const float*)d_in[16];
    const float* c2b = (const float*)d_in[17];
    const float* wih2 = (const float*)d_in[18];
    const float* whh2 = (const float*)d_in[19];
    const float* bih2 = (const float*)d_in[20];
    const float* bhh2 = (const float*)d_in[21];
    const float* kw = (const float*)d_in[22];
    const float* kb = (const float*)d_in[23];
    const float* vw = (const float*)d_in[24];
    const float* vb = (const float*)d_in[25];
    const float* wihd = (const float*)d_in[26];
    const float* whhd = (const float*)d_in[27];
    const float* bihd = (const float*)d_in[28];
    const float* bhhd = (const float*)d_in[29];
    const float* w1 = (const float*)d_in[30];
    const float* b1 = (const float*)d_in[31];
    const float* w2 = (const float*)d_in[32];
    const float* b2 = (const float*)d_in[33];
    const float* w3 = (const float*)d_in[34];
    const float* b3 = (const float*)d_in[35];
    const float* emb = (const float*)d_in[36];
    const float* sh0 = (const float*)d_in[37];
    const float* sc0 = (const float*)d_in[38];

    // ---- workspace plan (peak 139 MiB) ----
    char* ws = (char*)d_ws;
    const size_t MB = 1ull << 20;
    unsigned int* Wd = (unsigned int*)(ws + 0);                // 0-1 MiB: decoder weights [2][16][512][4]

    unsigned short* Hf_h   = (unsigned short*)(ws + 1 * MB);   // 1-33   f16 [t][b][128]
    unsigned short* Hr_h   = (unsigned short*)(ws + 33 * MB);  // 33-65
    float*          conv1o = (float*)(ws + 65 * MB);           // 65-97  f32 [b][t'][128]
    unsigned short* P2_h   = (unsigned short*)(ws + 1 * MB);   // 1-65   (over Hf/Hr)
    unsigned short* H2_h   = (unsigned short*)(ws + 65 * MB);  // 65-81  (over conv1o)
    float*          conv2o = (float*)(ws + 81 * MB);           // 81-97
    unsigned short* P3_h   = (unsigned short*)(ws + 97 * MB);  // 97-129
    float*          H3     = (float*)(ws + 1 * MB);            // 1-17   (over P2_h)
    float*          hkb    = (float*)(ws + 17 * MB);           // 17-33
    float*          hvT    = (float*)(ws + 33 * MB);           // 33-49
    unsigned int*   hvq    = (unsigned int*)(ws + 49 * MB);    // 49-57
    float*          Ypack  = (float*)(ws + 57 * MB);           // 57-89
    float*          Yp     = (float*)(ws + 89 * MB);           // 89-121
    float*          SHsave = (float*)(ws + 121 * MB);          // 121-130
    float*          Csave  = (float*)(ws + 130 * MB);          // 130-139

    // ---- pack decoder weights (once): h-path then c-path ----
    packq_k<<<128, 256, 0, stream>>>(whhd, Wd + 0,     128, 0,   16, 512);
    packq_k<<<128, 256, 0, stream>>>(wihd, Wd + 32768, 640, 512, 16, 512);

    // ---- encoder ----
    lstm1_k<<<64, 512, 0, stream>>>(utter, wih_f, whh_f, bih_f, bhh_f,
                                    wih_r, whh_r, bih_r, bhh_r, Hf_h, Hr_h);
    conv_k<256><<<dim3(64, 32), 128, 0, stream>>>(Hf_h, Hr_h, c1w, c1b, conv1o, 1024);
    gemm_k<<<dim3(1024, 8), 256, 0, stream>>>(conv1o, wih1, 128, bih1, bhh1,
                                              P2_h, 65536, 512, 128, 2, 0);
    lstm_k<<<32, 512, 0, stream>>>(P2_h, whh1, H2_h, 1024, 1);
    conv_k<128><<<dim3(64, 16), 128, 0, stream>>>(H2_h, nullptr, c2w, c2b, conv2o, 512);
    gemm_k<<<dim3(512, 8), 256, 0, stream>>>(conv2o, wih2, 128, bih2, bhh2,
                                             P3_h, 32768, 512, 128, 2, 0);
    lstm_k<<<32, 512, 0, stream>>>(P3_h, whh2, H3, 512, 0);
    gemm_k<<<dim3(512, 2), 256, 0, stream>>>(H3, kw, 128, kb, nullptr,
                                             hkb, 32768, 128, 128, 0, 0);
    gemm_k<<<dim3(512, 2), 256, 0, stream>>>(H3, vw, 128, vb, nullptr,
                                             hvT, 32768, 128, 128, 1, 512);
    packhv2_k<<<64, 1024, 0, stream>>>(hvT, hvq);
    packemb_k<<<16320, 512, 0, stream>>>(targets, emb, Ypack);
    gemm_k<<<dim3(255, 8), 256, 0, stream>>>(Ypack, wihd, 640, bihd, bhhd,
                                             Yp, 16320, 512, 512, 0, 0);
    // ---- decoder serial core + deferred MLP ----
    decoder_k<<<64, 512, 0, stream>>>(Yp, Wd, hkb, hvq, sh0, sc0, SHsave, Csave);
    mlp_k<<<4080, 256, 0, stream>>>(SHsave, Csave, w1, b1, w2, b2, w3, b3, (float*)d_out);
}

// Round 14
// 5133.380 us; speedup vs baseline: 1.4229x; 1.4229x over previous
//
#include <hip/hip_runtime.h>

// ---------------- types & helpers ----------------
typedef _Float16 half_t;
typedef _Float16 __attribute__((ext_vector_type(2))) half2_t;

__device__ __forceinline__ float fdot2_(half2_t a, half2_t b, float c) {
#if __has_builtin(__builtin_amdgcn_fdot2)
    return __builtin_amdgcn_fdot2(a, b, c, false);
#else
    return c + (float)a[0] * (float)b[0] + (float)a[1] * (float)b[1];
#endif
}
__device__ __forceinline__ half2_t h2(float a, float b) {
    half2_t r; r[0] = (half_t)a; r[1] = (half_t)b; return r;
}
__device__ __forceinline__ half2_t bc2(unsigned int u) {
    return __builtin_bit_cast(half2_t, u);
}
__device__ __forceinline__ unsigned int pk2(float a, float b) {
    return __builtin_bit_cast(unsigned int, h2(a, b));
}
__device__ __forceinline__ float sigm(float x) { return 1.0f / (1.0f + __expf(-x)); }
__device__ __forceinline__ float tanh_(float x) { return 1.0f - 2.0f / (1.0f + __expf(2.0f * x)); }
__device__ __forceinline__ unsigned int packbf2(float a, float b) {
    unsigned int ua = __float_as_uint(a);
    ua = (ua + 0x7fffu + ((ua >> 16) & 1u)) >> 16;
    unsigned int ub = __float_as_uint(b);
    ub = (ub + 0x7fffu + ((ub >> 16) & 1u)) >> 16;
    return ua | (ub << 16);
}
__device__ __forceinline__ float blo(unsigned int u) { return __uint_as_float(u << 16); }
__device__ __forceinline__ float bhi(unsigned int u) { return __uint_as_float(u & 0xffff0000u); }

// ---------------- LSTM layer 1 (bidir, K=40): R12 structure + 8-step chunked I/O ----------------
// Global loads (x) and stores (H) batched per 8-step chunk so the compiler's
// vmcnt(0)-before-barrier drain is paid once per chunk, not per step.
__global__ __launch_bounds__(512, 1) void lstm1_k(
    const float* __restrict__ utter,
    const float* __restrict__ wih_f, const float* __restrict__ whh_f,
    const float* __restrict__ bih_f, const float* __restrict__ bhh_f,
    const float* __restrict__ wih_r, const float* __restrict__ whh_r,
    const float* __restrict__ bih_r, const float* __restrict__ bhh_r,
    unsigned short* __restrict__ Hf, unsigned short* __restrict__ Hr)
{
    const int tid = threadIdx.x;
    const int b   = blockIdx.x & 63;
    const int dir = blockIdx.x >> 6;
    const float* wih = dir ? wih_r : wih_f;
    const float* whh = dir ? whh_r : whh_f;
    const float* bih = dir ? bih_r : bih_f;
    const float* bhh = dir ? bhh_r : bhh_f;
    unsigned short* Hout = dir ? Hr : Hf;

    __shared__ float acts[512];
    __shared__ __align__(16) half_t h_h[128];
    __shared__ __align__(16) half_t x2[2][8][48];   // double-buffered chunk of x (40 data + 8 pad)
    __shared__ __align__(16) float ring[8][128];    // H output ring (f32)

    const int j = tid;
    const int gt = tid >> 7;
    unsigned int wr2[64];
    {
        const float4* wp = reinterpret_cast<const float4*>(whh + j * 128);
#pragma unroll
        for (int m = 0; m < 32; ++m) {
            float4 v = wp[m];
            wr2[2 * m]     = pk2(v.x, v.y);
            wr2[2 * m + 1] = pk2(v.z, v.w);
        }
    }
    unsigned int wx2[20];
    {
        const float4* xp = reinterpret_cast<const float4*>(wih + j * 40);
#pragma unroll
        for (int q = 0; q < 10; ++q) {
            float4 v = xp[q];
            wx2[2 * q]     = pk2(v.x, v.y);
            wx2[2 * q + 1] = pk2(v.z, v.w);
        }
    }
    const float bias = bih[j] + bhh[j];
    float c = 0.0f;
    if (tid < 128) h_h[tid] = (half_t)0.0f;
    const int xs = tid / 40, xc = tid % 40;          // x-loader mapping (tid < 320)
    if (tid < 320) {
        int tt0 = dir ? (2047 - xs) : xs;
        x2[0][xs][xc] = (half_t)utter[((size_t)b * 2048 + tt0) * 40 + xc];
    }
    __syncthreads();

    for (int tc = 0; tc < 2048; tc += 8) {
        const int ph = (tc >> 3) & 1;
        // issue next-chunk x loads (latency hidden across the 8 steps)
        float xreg = 0.0f;
        if (tid < 320) {
            int tn = tc + 8 + xs; if (tn > 2047) tn = 2047;
            int ttn = dir ? (2047 - tn) : tn;
            xreg = utter[((size_t)b * 2048 + ttn) * 40 + xc];
        }
#pragma unroll
        for (int s = 0; s < 8; ++s) {
            float g0 = bias, g1 = 0.f, g2 = 0.f, g3 = 0.f;
            {
                const uint4* x4p = reinterpret_cast<const uint4*>(&x2[ph][s][0]);
#pragma unroll
                for (int q = 0; q < 5; ++q) {
                    uint4 u = x4p[q];
                    g0 = fdot2_(bc2(wx2[4 * q]),     bc2(u.x), g0);
                    g1 = fdot2_(bc2(wx2[4 * q + 1]), bc2(u.y), g1);
                    g2 = fdot2_(bc2(wx2[4 * q + 2]), bc2(u.z), g2);
                    g3 = fdot2_(bc2(wx2[4 * q + 3]), bc2(u.w), g3);
                }
                const uint4* h4p = reinterpret_cast<const uint4*>(h_h);
#pragma unroll
                for (int q = 0; q < 16; ++q) {
                    uint4 u = h4p[q];
                    g0 = fdot2_(bc2(wr2[4 * q]),     bc2(u.x), g0);
                    g1 = fdot2_(bc2(wr2[4 * q + 1]), bc2(u.y), g1);
                    g2 = fdot2_(bc2(wr2[4 * q + 2]), bc2(u.z), g2);
                    g3 = fdot2_(bc2(wr2[4 * q + 3]), bc2(u.w), g3);
                }
            }
            float g = (g0 + g1) + (g2 + g3);
            acts[j] = (gt == 2) ? tanh_(g) : sigm(g);
            __syncthreads();                           // B1 (LDS only)
            if (s == 7 && tid < 320)
                x2[ph ^ 1][xs][xc] = (half_t)xreg;     // stage next chunk's x (covered by B2)
            if (tid < 128) {
                float i_ = acts[tid];
                float f_ = acts[128 + tid];
                float g_ = acts[256 + tid];
                float o_ = acts[384 + tid];
                c = f_ * c + i_ * g_;
                float hh = o_ * tanh_(c);
                h_h[tid] = (half_t)hh;
                ring[s][tid] = hh;
            }
            __syncthreads();                           // B2 (LDS only)
        }
        // flush H ring: one coalesced store per thread, drained once next chunk
        {
            int s2 = tid >> 6, pr = tid & 63;
            int t = tc + s2;
            int tt = dir ? (2047 - t) : t;
            unsigned int v = pk2(ring[s2][2 * pr], ring[s2][2 * pr + 1]);
            reinterpret_cast<unsigned int*>(Hout)[((size_t)tt * 64 + b) * 64 + pr] = v;
        }
    }
}

// ---------------- LSTM layers 2/3: R12 structure + 8-step chunked I/O ----------------
__global__ __launch_bounds__(512, 1) void lstm_k(
    const unsigned short* __restrict__ Ph,   // [b][T][512] f16 bits
    const float* __restrict__ whh,
    void* __restrict__ Hout, int T, int outHalf)
{
    const int tid = threadIdx.x;
    const int b = blockIdx.x;
    const int j = tid;
    const int gt = tid >> 7;
    __shared__ float acts[512];
    __shared__ __align__(16) half_t h_h[128];
    __shared__ __align__(16) float ring[8][128];
    unsigned int wr2[64];
    {
        const float4* wp = reinterpret_cast<const float4*>(whh + j * 128);
#pragma unroll
        for (int m = 0; m < 32; ++m) {
            float4 v = wp[m];
            wr2[2 * m]     = pk2(v.x, v.y);
            wr2[2 * m + 1] = pk2(v.z, v.w);
        }
    }
    float c = 0.0f;
    if (tid < 128) h_h[tid] = (half_t)0.0f;
    const size_t pbase = (size_t)b * T;
    float pcur[8], pnext[8];
#pragma unroll
    for (int s = 0; s < 8; ++s)
        pcur[s] = (float)__builtin_bit_cast(half_t, Ph[(pbase + s) * 512 + j]);
    __syncthreads();

    for (int tc = 0; tc < T; tc += 8) {
        // issue next-chunk P loads (latency hidden across the 8 steps)
#pragma unroll
        for (int s = 0; s < 8; ++s) {
            int tn = tc + 8 + s; if (tn > T - 1) tn = T - 1;
            pnext[s] = (float)__builtin_bit_cast(half_t, Ph[(pbase + tn) * 512 + j]);
        }
#pragma unroll
        for (int s = 0; s < 8; ++s) {
            float g0 = pcur[s], g1 = 0.f, g2 = 0.f, g3 = 0.f;
            const uint4* h4p = reinterpret_cast<const uint4*>(h_h);
#pragma unroll
            for (int q = 0; q < 16; ++q) {
                uint4 u = h4p[q];
                g0 = fdot2_(bc2(wr2[4 * q]),     bc2(u.x), g0);
                g1 = fdot2_(bc2(wr2[4 * q + 1]), bc2(u.y), g1);
                g2 = fdot2_(bc2(wr2[4 * q + 2]), bc2(u.z), g2);
                g3 = fdot2_(bc2(wr2[4 * q + 3]), bc2(u.w), g3);
            }
            float g = (g0 + g1) + (g2 + g3);
            acts[j] = (gt == 2) ? tanh_(g) : sigm(g);
            __syncthreads();                           // B1 (LDS only)
            if (tid < 128) {
                float i_ = acts[tid];
                float f_ = acts[128 + tid];
                float g_ = acts[256 + tid];
                float o_ = acts[384 + tid];
                c = f_ * c + i_ * g_;
                float hh = o_ * tanh_(c);
                h_h[tid] = (half_t)hh;
                ring[s][tid] = hh;
            }
            __syncthreads();                           // B2 (LDS only)
        }
        // flush H ring
        {
            int s2 = tid >> 6, pr = tid & 63;
            int t = tc + s2;
            if (outHalf) {
                unsigned int v = pk2(ring[s2][2 * pr], ring[s2][2 * pr + 1]);
                reinterpret_cast<unsigned int*>(Hout)[((size_t)t * 64 + b) * 64 + pr] = v;
            } else {
                float2 v = make_float2(ring[s2][2 * pr], ring[s2][2 * pr + 1]);
                *reinterpret_cast<float2*>(
                    &reinterpret_cast<float*>(Hout)[((size_t)t * 64 + b) * 128 + 2 * pr]) = v;
            }
        }
#pragma unroll
        for (int s = 0; s < 8; ++s) pcur[s] = pnext[s];
    }
}

// ---------------- conv1d kernel=2 stride=2, f16 inputs ----------------
template <int CIN>
__global__ __launch_bounds__(128) void conv_k(
    const unsigned short* __restrict__ HA, const unsigned short* __restrict__ HB,
    const float* __restrict__ W, const float* __restrict__ bias,
    float* __restrict__ out, int Tout)
{
    __shared__ __align__(16) float xin[64 * CIN];
    const int b = blockIdx.x;
    const int t0 = blockIdx.y * 32;
    const int tid = threadIdx.x;
    for (int idx = tid; idx < 64 * CIN; idx += 128) {
        int tl = idx / CIN, ci = idx % CIN;
        int tau = t0 * 2 + tl;
        unsigned short u;
        if constexpr (CIN == 256) {
            u = (ci < 128) ? HA[(size_t)tau * 8192 + b * 128 + ci]
                           : HB[(size_t)tau * 8192 + b * 128 + (ci - 128)];
        } else {
            u = HA[(size_t)tau * 8192 + b * 128 + ci];
        }
        xin[idx] = (float)__builtin_bit_cast(half_t, u);
    }
    __syncthreads();
    const int co = tid;
    float acc[32];
#pragma unroll
    for (int u = 0; u < 32; ++u) acc[u] = 0.0f;
    const float4* Wrow4 = reinterpret_cast<const float4*>(W + (size_t)co * 2 * CIN);
    const float4* xin4 = reinterpret_cast<const float4*>(xin);
    for (int c4 = 0; c4 < CIN / 4; ++c4) {
        float4 wA = Wrow4[2 * c4];
        float4 wB = Wrow4[2 * c4 + 1];
#pragma unroll
        for (int u = 0; u < 32; ++u) {
            float4 x0 = xin4[(2 * u) * (CIN / 4) + c4];
            float4 x1 = xin4[(2 * u + 1) * (CIN / 4) + c4];
            acc[u] += wA.x * x0.x + wA.y * x1.x + wA.z * x0.y + wA.w * x1.y
                    + wB.x * x0.z + wB.y * x1.z + wB.z * x0.w + wB.w * x1.w;
        }
    }
    float bs = bias[co];
#pragma unroll
    for (int u = 0; u < 32; ++u)
        out[((size_t)b * Tout + t0 + u) * 128 + co] = acc[u] + bs;
}

// ---------------- generic f32 GEMM ----------------
// mode 0: C f32 [m][N]; mode 1: transposed f32 C[(b*N+n)*Tdim+t], m=t*64+b; mode 2: C f16 [m][N]
__global__ __launch_bounds__(256) void gemm_k(
    const float* __restrict__ A, const float* __restrict__ W, int ldw,
    const float* __restrict__ bias1, const float* __restrict__ bias2,
    void* __restrict__ C, int M, int N, int K, int mode, int Tdim)
{
    __shared__ __align__(16) float As[16][68];
    __shared__ __align__(16) float Ws[16][68];
    const int tid = threadIdx.x;
    const int m0 = blockIdx.x * 64, n0 = blockIdx.y * 64;
    const int kk = tid & 15, mm = tid >> 4;
    const int tm = tid & 15, tn = tid >> 4;
    float acc[4][4];
#pragma unroll
    for (int i = 0; i < 4; ++i)
#pragma unroll
        for (int jj = 0; jj < 4; ++jj) acc[i][jj] = 0.0f;

    for (int k0 = 0; k0 < K; k0 += 16) {
#pragma unroll
        for (int r = 0; r < 4; ++r) {
            As[kk][mm + 16 * r] = A[(size_t)(m0 + mm + 16 * r) * K + k0 + kk];
            Ws[kk][mm + 16 * r] = W[(size_t)(n0 + mm + 16 * r) * ldw + k0 + kk];
        }
        __syncthreads();
#pragma unroll
        for (int q = 0; q < 16; ++q) {
            float4 a = reinterpret_cast<const float4*>(&As[q][0])[tm];
            float4 w = reinterpret_cast<const float4*>(&Ws[q][0])[tn];
            acc[0][0] += a.x * w.x; acc[0][1] += a.x * w.y; acc[0][2] += a.x * w.z; acc[0][3] += a.x * w.w;
            acc[1][0] += a.y * w.x; acc[1][1] += a.y * w.y; acc[1][2] += a.y * w.z; acc[1][3] += a.y * w.w;
            acc[2][0] += a.z * w.x; acc[2][1] += a.z * w.y; acc[2][2] += a.z * w.z; acc[2][3] += a.z * w.w;
            acc[3][0] += a.w * w.x; acc[3][1] += a.w * w.y; acc[3][2] += a.w * w.z; acc[3][3] += a.w * w.w;
        }
        __syncthreads();
    }
    float bv[4];
#pragma unroll
    for (int jj = 0; jj < 4; ++jj) {
        int n = n0 + tn * 4 + jj;
        float v = 0.0f;
        if (bias1) v += bias1[n];
        if (bias2) v += bias2[n];
        bv[jj] = v;
    }
#pragma unroll
    for (int i = 0; i < 4; ++i) {
        int m = m0 + tm * 4 + i;
#pragma unroll
        for (int jj = 0; jj < 4; ++jj) {
            int n = n0 + tn * 4 + jj;
            float v = acc[i][jj] + bv[jj];
            if (mode == 0) {
                ((float*)C)[(size_t)m * N + n] = v;
            } else if (mode == 1) {
                int bb = m & 63, tt = m >> 6;
                ((float*)C)[((size_t)bb * N + n) * Tdim + tt] = v;
            } else {
                ((unsigned short*)C)[(size_t)m * N + n] =
                    __builtin_bit_cast(unsigned short, (half_t)v);
            }
        }
    }
}

// ---------------- gather emb[targets] rows ----------------
__global__ __launch_bounds__(512) void packemb_k(
    const int* __restrict__ targets, const float* __restrict__ emb,
    float* __restrict__ Ypack)
{
    int m = blockIdx.x;  // l*64 + b
    int l = m >> 6, b = m & 63;
    int tgt = targets[b * 256 + l];
    Ypack[(size_t)m * 512 + threadIdx.x] = emb[(size_t)tgt * 512 + threadIdx.x];
}

// ---------------- pack: rows -> coalesced [nq][rows][uint4] (decoder weights) ----------------
__global__ __launch_bounds__(256) void packq_k(
    const float* __restrict__ src, unsigned int* __restrict__ dst,
    int srcCols, int colOff, int nq, int rows)
{
    int g = blockIdx.x * 256 + threadIdx.x;
    if (g >= rows * nq * 4) return;
    int k = g & 3, t = g >> 2;
    int j = t % rows, q = t / rows;
    int p = q * 4 + k;
    const float* s = src + (size_t)j * srcCols + colOff + 2 * p;
    dst[g] = pk2(s[0], s[1]);
}

// ---------------- pack hv: hvT f32 [b][d][t] -> bf16 pairs [b][tq][d] ----------------
__global__ __launch_bounds__(1024) void packhv2_k(
    const float* __restrict__ hvT, unsigned int* __restrict__ hvq)
{
    int b = blockIdx.x;
    for (int it = 0; it < 32; ++it) {
        int idx = it * 1024 + threadIdx.x;       // 32768 = 256 tq x 128 d
        int tq = idx >> 7, d = idx & 127;
        const float* s = hvT + ((size_t)b * 128 + d) * 512 + 2 * tq;
        hvq[(size_t)b * 32768 + idx] = packbf2(s[0], s[1]);
    }
}

// ---------------- attention decoder (R12): 512 thr, h-path weights in regs ----------------
__global__ __launch_bounds__(512, 1) void decoder_k(
    const float* __restrict__ Yp,
    const unsigned int* __restrict__ Wd,     // [2 path][16 q][512 j][4 k] u32
    const float* __restrict__ hk,            // f32 [t*64+b][128]
    const unsigned int* __restrict__ hvq,    // [b][256 tq][128 d] bf16 pairs
    const float* __restrict__ sh0, const float* __restrict__ sc0,
    float* __restrict__ SHs, float* __restrict__ Cs)
{
    __shared__ unsigned int hk_lds[512][66];   // 135168 B
    __shared__ float acts[512];
    __shared__ float pfl[512];
    __shared__ __align__(16) half_t sh_h[128];
    __shared__ __align__(16) float sc_f[128];
    __shared__ __align__(16) half_t c_h[128];
    __shared__ __align__(16) float att[512];
    __shared__ float red[8];

    const int tid = threadIdx.x;
    const int b = blockIdx.x;
    const int gt = tid >> 7;

    uint4 wh[16];
    {
        const uint4* W4 = reinterpret_cast<const uint4*>(Wd);
#pragma unroll
        for (int q = 0; q < 16; ++q) wh[q] = W4[q * 512 + tid];
    }
    const uint4* Wc4 = reinterpret_cast<const uint4*>(Wd) + 8192;  // c-path, streamed

    {
        const float4* hp = reinterpret_cast<const float4*>(hk + ((size_t)tid * 64 + b) * 128);
#pragma unroll
        for (int q = 0; q < 32; ++q) {
            float4 v = hp[q];
            hk_lds[tid][2 * q]     = packbf2(v.x, v.y);
            hk_lds[tid][2 * q + 1] = packbf2(v.z, v.w);
        }
    }
    float sc_r = 0.0f;
    if (tid < 128) {
        sh_h[tid] = (half_t)sh0[b * 128 + tid];
        sc_r = sc0[b * 128 + tid];
        sc_f[tid] = sc_r;
        c_h[tid] = (half_t)0.0f;
    }
    __syncthreads();

    const int wid = tid >> 6, lane = tid & 63;
    const int g4 = tid >> 7, d = tid & 127;
    const unsigned int* hvp = hvq + (size_t)b * 32768 + (size_t)(g4 * 64) * 128 + d;
    const float2* att2 = reinterpret_cast<const float2*>(att);
    float yp_cur = Yp[(size_t)b * 512 + tid];

    for (int l = 0; l < 255; ++l) {
        int lnxt = (l + 1 < 255) ? (l + 1) : l;
        float yp_nxt = Yp[((size_t)lnxt * 64 + b) * 512 + tid];
        {
            float g0 = yp_cur, g1 = 0.f, g2 = 0.f, g3 = 0.f;
            const uint4* s4 = reinterpret_cast<const uint4*>(sh_h);
#pragma unroll
            for (int q = 0; q < 16; ++q) {
                uint4 u = s4[q];
                g0 = fdot2_(bc2(wh[q].x), bc2(u.x), g0);
                g1 = fdot2_(bc2(wh[q].y), bc2(u.y), g1);
                g2 = fdot2_(bc2(wh[q].z), bc2(u.z), g2);
                g3 = fdot2_(bc2(wh[q].w), bc2(u.w), g3);
            }
            const uint4* c4 = reinterpret_cast<const uint4*>(c_h);
#pragma unroll
            for (int q = 0; q < 16; ++q) {
                uint4 w = Wc4[q * 512 + tid];
                uint4 u = c4[q];
                g0 = fdot2_(bc2(w.x), bc2(u.x), g0);
                g1 = fdot2_(bc2(w.y), bc2(u.y), g1);
                g2 = fdot2_(bc2(w.z), bc2(u.z), g2);
                g3 = fdot2_(bc2(w.w), bc2(u.w), g3);
            }
            float g = (g0 + g1) + (g2 + g3);
            acts[tid] = (gt == 2) ? tanh_(g) : sigm(g);
        }
        __syncthreads();                                   // B1
        if (tid < 128) {
            float i_ = acts[tid];
            float f_ = acts[128 + tid];
            float g_ = acts[256 + tid];
            float o_ = acts[384 + tid];
            sc_r = f_ * sc_r + i_ * g_;
            float hh = o_ * tanh_(sc_r);
            sh_h[tid] = (half_t)hh;
            sc_f[tid] = sc_r;
            SHs[((size_t)l * 64 + b) * 128 + tid] = hh;
        }
        __syncthreads();                                   // B2
        {
            float e0 = 0.f, e1 = 0.f, e2 = 0.f, e3 = 0.f;
            const uint2* hkr = reinterpret_cast<const uint2*>(&hk_lds[tid][0]);
            const float4* sc4 = reinterpret_cast<const float4*>(sc_f);
#pragma unroll
            for (int q = 0; q < 32; ++q) {
                uint2 u = hkr[q];
                float4 s = sc4[q];
                e0 += blo(u.x) * s.x; e1 += bhi(u.x) * s.y;
                e2 += blo(u.y) * s.z; e3 += bhi(u.y) * s.w;
            }
            float p = __expf((e0 + e1) + (e2 + e3));
            att[tid] = p;
            float ps = p;
#pragma unroll
            for (int off = 32; off; off >>= 1) ps += __shfl_xor(ps, off);
            if (lane == 0) red[wid] = ps;
        }
        __syncthreads();                                   // B3
        {
            float a0 = 0.f, a1 = 0.f;
#pragma unroll 8
            for (int i = 0; i < 64; i += 2) {
                unsigned int u0 = hvp[(size_t)i * 128];
                unsigned int u1 = hvp[(size_t)(i + 1) * 128];
                float2 w0 = att2[g4 * 64 + i];
                float2 w1 = att2[g4 * 64 + i + 1];
                a0 += blo(u0) * w0.x + bhi(u0) * w0.y;
                a1 += blo(u1) * w1.x + bhi(u1) * w1.y;
            }
            pfl[tid] = a0 + a1;
        }
        __syncthreads();                                   // B4
        if (tid < 128) {
            float S = ((red[0] + red[1]) + (red[2] + red[3]))
                    + ((red[4] + red[5]) + (red[6] + red[7]));
            float cv = (pfl[tid] + pfl[128 + tid] + pfl[256 + tid] + pfl[384 + tid]) / S;
            c_h[tid] = (half_t)cv;
            Cs[((size_t)l * 64 + b) * 128 + tid] = cv;
        }
        yp_cur = yp_nxt;
        __syncthreads();                                   // B5
    }
}

// ---------------- deferred output MLP + softmax ----------------
__global__ __launch_bounds__(256) void mlp_k(
    const float* __restrict__ SHs, const float* __restrict__ Cs,
    const float* __restrict__ w1, const float* __restrict__ b1,
    const float* __restrict__ w2, const float* __restrict__ b2,
    const float* __restrict__ w3, const float* __restrict__ b3,
    float* __restrict__ out)
{
    __shared__ float o_l[4][34];
    const int sub = threadIdx.x >> 6, lane = threadIdx.x & 63;
    const int m = blockIdx.x * 4 + sub;     // l*64 + b
    const int l = m >> 6, b = m & 63;
    if (lane < 34) {
        float o1 = b1[lane] + b2[lane];
        const float4* w1r = reinterpret_cast<const float4*>(w1 + lane * 128);
        const float4* w2r = reinterpret_cast<const float4*>(w2 + lane * 128);
        const float4* sh4 = reinterpret_cast<const float4*>(SHs + (size_t)m * 128);
        const float4* c4  = reinterpret_cast<const float4*>(Cs + (size_t)m * 128);
#pragma unroll 8
        for (int q = 0; q < 32; ++q) {
            float4 a = w1r[q], h = sh4[q], w = w2r[q], cc = c4[q];
            o1 += a.x * h.x + a.y * h.y + a.z * h.z + a.w * h.w
                + w.x * cc.x + w.y * cc.y + w.z * cc.z + w.w * cc.w;
        }
        o_l[sub][lane] = fmaxf(o1, 0.0f);
    }
    __syncthreads();
    if (lane < 34) {
        float zz = b3[lane];
        const float* w3r = w3 + lane * 34;
        for (int v = 0; v < 34; ++v) zz += w3r[v] * o_l[sub][v];
        __syncthreads();
        o_l[sub][lane] = zz;
        __syncthreads();
        float zm = o_l[sub][0];
        for (int v = 1; v < 34; ++v) zm = fmaxf(zm, o_l[sub][v]);
        float Ssum = 0.0f;
        for (int v = 0; v < 34; ++v) Ssum += __expf(o_l[sub][v] - zm);
        out[((size_t)b * 255 + l) * 34 + lane] = __expf(zz - zm) / Ssum;
    }
}

// ---------------- launch ----------------
extern "C" void kernel_launch(void* const* d_in, const int* in_sizes, int n_in,
                              void* d_out, int out_size, void* d_ws, size_t ws_size,
                              hipStream_t stream) {
    (void)in_sizes; (void)n_in; (void)out_size; (void)ws_size;
    const float* utter = (const float*)d_in[0];
    const int*   targets = (const int*)d_in[1];
    const float* wih_f = (const float*)d_in[2];
    const float* whh_f = (const float*)d_in[3];
    const float* bih_f = (const float*)d_in[4];
    const float* bhh_f = (const float*)d_in[5];
    const float* wih_r = (const float*)d_in[6];
    const float* whh_r = (const float*)d_in[7];
    const float* bih_r = (const float*)d_in[8];
    const float* bhh_r = (const float*)d_in[9];
    const float* c1w = (const float*)d_in[10];
    const float* c1b = (const float*)d_in[11];
    const float* wih1 = (const float*)d_in[12];
    const float* whh1 = (const float*)d_in[13];
    const float* bih1 = (const float*)d_in[14];
    const float* bhh1 = (const float*)d_in[15];
    const float* c2w = (const float*)d_in[16];
    const float* c2b = (const float*)d_in[17];
    const float* wih2 = (const float*)d_in[18];
    const float* whh2 = (const float*)d_in[19];
    const float* bih2 = (const float*)d_in[20];
    const float* bhh2 = (const float*)d_in[21];
    const float* kw = (const float*)d_in[22];
    const float* kb = (const float*)d_in[23];
    const float* vw = (const float*)d_in[24];
    const float* vb = (const float*)d_in[25];
    const float* wihd = (const float*)d_in[26];
    const float* whhd = (const float*)d_in[27];
    const float* bihd = (const float*)d_in[28];
    const float* bhhd = (const float*)d_in[29];
    const float* w1 = (const float*)d_in[30];
    const float* b1 = (const float*)d_in[31];
    const float* w2 = (const float*)d_in[32];
    const float* b2 = (const float*)d_in[33];
    const float* w3 = (const float*)d_in[34];
    const float* b3 = (const float*)d_in[35];
    const float* emb = (const float*)d_in[36];
    const float* sh0 = (const float*)d_in[37];
    const float* sc0 = (const float*)d_in[38];

    // ---- workspace plan (peak 139 MiB) ----
    char* ws = (char*)d_ws;
    const size_t MB = 1ull << 20;
    unsigned int* Wd = (unsigned int*)(ws + 0);                // 0-1 MiB: decoder weights [2][16][512][4]

    unsigned short* Hf_h   = (unsigned short*)(ws + 1 * MB);   // 1-33   f16 [t][b][128]
    unsigned short* Hr_h   = (unsigned short*)(ws + 33 * MB);  // 33-65
    float*          conv1o = (float*)(ws + 65 * MB);           // 65-97  f32 [b][t'][128]
    unsigned short* P2_h   = (unsigned short*)(ws + 1 * MB);   // 1-65   (over Hf/Hr)
    unsigned short* H2_h   = (unsigned short*)(ws + 65 * MB);  // 65-81  (over conv1o)
    float*          conv2o = (float*)(ws + 81 * MB);           // 81-97
    unsigned short* P3_h   = (unsigned short*)(ws + 97 * MB);  // 97-129
    float*          H3     = (float*)(ws + 1 * MB);            // 1-17   (over P2_h)
    float*          hkb    = (float*)(ws + 17 * MB);           // 17-33
    float*          hvT    = (float*)(ws + 33 * MB);           // 33-49
    unsigned int*   hvq    = (unsigned int*)(ws + 49 * MB);    // 49-57
    float*          Ypack  = (float*)(ws + 57 * MB);           // 57-89
    float*          Yp     = (float*)(ws + 89 * MB);           // 89-121
    float*          SHsave = (float*)(ws + 121 * MB);          // 121-130
    float*          Csave  = (float*)(ws + 130 * MB);          // 130-139

    // ---- pack decoder weights (once): h-path then c-path ----
    packq_k<<<128, 256, 0, stream>>>(whhd, Wd + 0,     128, 0,   16, 512);
    packq_k<<<128, 256, 0, stream>>>(wihd, Wd + 32768, 640, 512, 16, 512);

    // ---- encoder ----
    lstm1_k<<<128, 512, 0, stream>>>(utter, wih_f, whh_f, bih_f, bhh_f,
                                     wih_r, whh_r, bih_r, bhh_r, Hf_h, Hr_h);
    conv_k<256><<<dim3(64, 32), 128, 0, stream>>>(Hf_h, Hr_h, c1w, c1b, conv1o, 1024);
    gemm_k<<<dim3(1024, 8), 256, 0, stream>>>(conv1o, wih1, 128, bih1, bhh1,
                                              P2_h, 65536, 512, 128, 2, 0);
    lstm_k<<<64, 512, 0, stream>>>(P2_h, whh1, H2_h, 1024, 1);
    conv_k<128><<<dim3(64, 16), 128, 0, stream>>>(H2_h, nullptr, c2w, c2b, conv2o, 512);
    gemm_k<<<dim3(512, 8), 256, 0, stream>>>(conv2o, wih2, 128, bih2, bhh2,
                                             P3_h, 32768, 512, 128, 2, 0);
    lstm_k<<<64, 512, 0, stream>>>(P3_h, whh2, H3, 512, 0);
    gemm_k<<<dim3(512, 2), 256, 0, stream>>>(H3, kw, 128, kb, nullptr,
                                             hkb, 32768, 128, 128, 0, 0);
    gemm_k<<<dim3(512, 2), 256, 0, stream>>>(H3, vw, 128, vb, nullptr,
                                             hvT, 32768, 128, 128, 1, 512);
    packhv2_k<<<64, 1024, 0, stream>>>(hvT, hvq);
    packemb_k<<<16320, 512, 0, stream>>>(targets, emb, Ypack);
    gemm_k<<<dim3(255, 8), 256, 0, stream>>>(Ypack, wihd, 640, bihd, bhhd,
                                             Yp, 16320, 512, 512, 0, 0);
    // ---- decoder serial core + deferred MLP ----
    decoder_k<<<64, 512, 0, stream>>>(Yp, Wd, hkb, hvq, sh0, sc0, SHsave, Csave);
    mlp_k<<<4080, 256, 0, stream>>>(SHsave, Csave, w1, b1, w2, b2, w3, b3, (float*)d_out);
}